// Round 8
// baseline (379.548 us; speedup 1.0000x reference)
//
#include <hip/hip_runtime.h>
#include <cmath>

// ConformalModelLogits forward (randomized=True, allow_zero_sets=False).
// One 64-lane wave per row. C=1000 -> 250 float4 chunks; lane l owns chunks
// {l, l+64, l+128, l+192} = 16 classes in registers. No LDS tiles, no barriers.
//
// Monotone threshold => prediction set is a sorted prefix; penalties bound its
// length (<=10 here), so ~10 wave-argmax pops replace the full 1000-sort.
//
// R4: 180us, VALUBusy 73.6% -> extraction was VALU hog.
// R5: u64 keys + top-2 + shfl penalties -> ~119us, absmax 0.0.
// R6/R7: f32-max butterfly + ballot fast path (u64 butterfly only on exact
//     score ties), slimmer top-2, nontemporal stores via clang ext-vector type
//     (HIP float4 is a class; the builtin requires a real vector type).

typedef float f32x4 __attribute__((ext_vector_type(4)));

__global__ __launch_bounds__(256) void conformal_kernel(
    const float* __restrict__ logits,
    const float* __restrict__ penalties,
    const float* __restrict__ u,
    const float* __restrict__ Tptr,
    const float* __restrict__ Qptr,
    float* __restrict__ outL,
    float* __restrict__ outM,
    float* __restrict__ outS,
    int B, int C)
{
    const int lane = threadIdx.x & 63;
    const int row  = blockIdx.x * 4 + (threadIdx.x >> 6);
    if (row >= B) return;

    const float tau = Qptr[0];
    const float Tv  = Tptr[0];
    const int   nch = C >> 2;                  // 250 float4 chunks per row
    const f32x4* xrow4 = reinterpret_cast<const f32x4*>(logits + (size_t)row * C);

    const float pl = penalties[lane < C ? lane : 0];   // pcs increments via shfl
    const float uu = u[row];

    f32x4 xv[4];
    float sc[16];
    bool  valid[4];

    // ---- load + z = x/T, row max ----  (numerics identical to R4/R5)
    float m = -INFINITY;
    #pragma unroll
    for (int s = 0; s < 4; ++s) {
        const int ch = lane + (s << 6);
        valid[s] = (ch < nch);
        if (valid[s]) {
            const f32x4 q = xrow4[ch];
            xv[s] = q;
            const float z0 = q.x / Tv, z1 = q.y / Tv, z2 = q.z / Tv, z3 = q.w / Tv;
            sc[s*4+0] = z0; sc[s*4+1] = z1; sc[s*4+2] = z2; sc[s*4+3] = z3;
            m = fmaxf(m, fmaxf(fmaxf(z0, z1), fmaxf(z2, z3)));
        } else {
            xv[s] = (f32x4){0.f, 0.f, 0.f, 0.f};
            sc[s*4+0] = -INFINITY; sc[s*4+1] = -INFINITY;
            sc[s*4+2] = -INFINITY; sc[s*4+3] = -INFINITY;
        }
    }
    #pragma unroll
    for (int off = 32; off > 0; off >>= 1)
        m = fmaxf(m, __shfl_xor(m, off, 64));

    // ---- exp + sum -> softmax scores ----
    float sum = 0.f;
    #pragma unroll
    for (int i = 0; i < 16; ++i) {
        const float e = expf(sc[i] - m);       // -INF tail -> 0
        sc[i] = e;
        sum += e;
    }
    #pragma unroll
    for (int off = 32; off > 0; off >>= 1)
        sum += __shfl_xor(sum, off, 64);
    #pragma unroll
    for (int i = 0; i < 16; ++i)
        sc[i] = sc[i] / sum;                   // exact IEEE div, matches jax

    // ---- per-lane top-2 precompute (score, class), smaller class wins ties ----
    unsigned rem = 0u;
    #pragma unroll
    for (int s = 0; s < 4; ++s)
        if (valid[s]) rem |= (0xFu << (s << 2));
    unsigned memb = 0u;

    float v1 = -1.0f, v2 = -1.0f;              // every lane has >=12 valid slots
    int   c1 = 0x7FFFFFFF, c2 = 0x7FFFFFFF;
    #pragma unroll
    for (int i = 0; i < 16; ++i) {
        if (rem & (1u << i)) {
            const int s = i >> 2, j = i & 3;
            const int cls = ((lane + (s << 6)) << 2) + j;   // increasing order
            const float v = sc[i];
            if (v > v1)      { v2 = v1; c2 = c1; v1 = v; c1 = cls; }
            else if (v > v2) { v2 = v; c2 = cls; }
        }
    }

    float hv = v1; int hi = c1;                // lane's best remaining (head)
    int npop = 0;

    float cum = 0.f, pen = 0.f;
    int   k = 0;
    int   szb, last_idx;
    float V;

    while (true) {
        // ---- wave argmax over head scores: f32 max butterfly ----
        float wv = hv;
        #pragma unroll
        for (int off = 32; off > 0; off >>= 1)
            wv = fmaxf(wv, __shfl_xor(wv, off, 64));

        const unsigned long long tie = __ballot(hv == wv);
        int winner_lane;
        float val; int idx;
        if (__popcll(tie) == 1) {              // unique winner (common path)
            winner_lane = __ffsll((long long)tie) - 1;
            val = wv;
            idx = __shfl(hi, winner_lane, 64);
        } else {
            // exact score tie across lanes: u64 packed-key butterfly, smaller
            // class wins (argsort-stable). Guard exhausted heads (hv < 0).
            unsigned long long key = (hv < 0.0f) ? 0ull :
                (((unsigned long long)__float_as_uint(hv) << 32) |
                 (unsigned long long)(0xFFFFFFFFu - (unsigned)hi));
            unsigned long long wk = key;
            #pragma unroll
            for (int off = 32; off > 0; off >>= 1) {
                const unsigned long long ok = __shfl_xor(wk, off, 64);
                if (ok > wk) wk = ok;
            }
            val = __uint_as_float((unsigned)(wk >> 32));
            idx = (int)(0xFFFFFFFFu - (unsigned)(wk & 0xFFFFFFFFull));
            winner_lane = __ffsll((long long)__ballot(key == wk)) - 1;
        }

        // ---- owner (winner) lane: mark extracted, refill head ----
        if (lane == winner_lane) {
            const int ch   = idx >> 2;
            const int slot = ((ch >> 6) << 2) | (idx & 3);
            rem  &= ~(1u << slot);
            memb |=  (1u << slot);
            if (npop == 0) {
                hv = v2; hi = c2;              // true 2nd-best of this lane
            } else {
                // rare: 3rd+ pop from one lane -> rescan remaining slots
                float bv = -1.0f; int bc = 0x7FFFFFFF;
                #pragma unroll
                for (int i = 0; i < 16; ++i) {
                    if (rem & (1u << i)) {
                        const int s = i >> 2, j = i & 3;
                        const int cls = ((lane + (s << 6)) << 2) + j;
                        const float v = sc[i];
                        if (v > bv || (v == bv && cls < bc)) { bv = v; bc = cls; }
                    }
                }
                hv = bv; hi = bc;              // -1 sentinel if exhausted
            }
            ++npop;
        }
        last_idx = idx;

        const float pk   = (k < 64) ? __shfl(pl, k, 64) : penalties[k];
        const float penk = pen + pk;           // pcs[k]
        if (cum + val + penk <= tau) {
            cum += val; pen = penk; ++k;
            if (k >= C) {                      // all positions passed
                szb = C;
                V = (tau - (cum - val) - penk) / val;   // position C-1
                break;
            }
        } else {
            szb = k + 1;                       // first failure at k
            V = (tau - cum - penk) / val;      // cum_s - ord_s = cum
            break;
        }
    }

    // ---- randomized shrink, clamps ----
    int sizes = szb - ((uu >= V) ? 1 : 0);
    const bool full = (tau == 1.0f);
    if (full) sizes = C;
    if (sizes < 1) sizes = 1;
    const bool drop_last = (!full) && (sizes < szb);

    // ---- fused outputs: logits copy, mask, sizes (nontemporal) ----
    f32x4* oL4 = reinterpret_cast<f32x4*>(outL + (size_t)row * C);
    f32x4* oM4 = reinterpret_cast<f32x4*>(outM + (size_t)row * C);
    #pragma unroll
    for (int s = 0; s < 4; ++s) {
        const int ch = lane + (s << 6);
        if (!valid[s]) continue;
        __builtin_nontemporal_store(xv[s], &oL4[ch]);
        f32x4 mk;
        #pragma unroll
        for (int j = 0; j < 4; ++j) {
            const int slot = (s << 2) | j;
            const int cls  = (ch << 2) | j;
            const bool in_set = full ||
                (((memb >> slot) & 1u) && !(drop_last && cls == last_idx));
            mk[j] = in_set ? 1.0f : 0.0f;
        }
        __builtin_nontemporal_store(mk, &oM4[ch]);
    }
    if (lane == 0) outS[row] = (float)sizes;
}

extern "C" void kernel_launch(void* const* d_in, const int* in_sizes, int n_in,
                              void* d_out, int out_size, void* d_ws, size_t ws_size,
                              hipStream_t stream) {
    const float* logits    = (const float*)d_in[0];
    const float* penalties = (const float*)d_in[1];
    const float* u         = (const float*)d_in[2];
    const float* T         = (const float*)d_in[3];
    const float* Qhat      = (const float*)d_in[4];

    const int C = in_sizes[1];   // penalties: (1, C)
    const int B = in_sizes[2];   // u: (B,)

    float* out  = (float*)d_out;
    float* outL = out;                              // [B*C] logits pass-through
    float* outM = out + (size_t)B * C;              // [B*C] set mask as float
    float* outS = out + 2 * (size_t)B * C;          // [B]   sizes as float

    const int blocks = (B + 3) / 4;                 // 4 rows (waves) per block
    conformal_kernel<<<blocks, 256, 0, stream>>>(
        logits, penalties, u, T, Qhat, outL, outM, outS, B, C);
}